// Round 15
// baseline (1615.207 us; speedup 1.0000x reference)
//
#include <hip/hip_runtime.h>

typedef unsigned short u16;
typedef __attribute__((ext_vector_type(4))) float f32x4;
typedef __attribute__((ext_vector_type(4))) u16 u16x4;
typedef __attribute__((ext_vector_type(8))) u16 u16x8;
typedef __attribute__((ext_vector_type(8))) short short8;

template <int V> struct IC { static constexpr int value = V; };

__device__ __forceinline__ u16 f2bf(float f) {
  unsigned int u = __builtin_bit_cast(unsigned int, f);
  u += 0x7FFFu + ((u >> 16) & 1u);   // RNE
  return (u16)(u >> 16);
}
__device__ __forceinline__ float bf2f(u16 b) {
  unsigned int u = ((unsigned int)b) << 16;
  return __builtin_bit_cast(float, u);
}

// async global->LDS, 16B per lane; dest must be wave-linear (base + lane*16)
__device__ __forceinline__ void gld16(const void* g, void* l) {
  __builtin_amdgcn_global_load_lds(
      (const __attribute__((address_space(1))) unsigned int*)g,
      (__attribute__((address_space(3))) unsigned int*)l, 16, 0, 0);
}

template <int N>
__device__ __forceinline__ void boundary() {
  asm volatile("s_waitcnt vmcnt(%0)" ::"n"(N) : "memory");
  __builtin_amdgcn_s_barrier();
  asm volatile("" ::: "memory");
  __builtin_amdgcn_sched_barrier(0);
}

// ---------------- conversion / transpose ----------------

__global__ __launch_bounds__(256) void cvt_f32_bf16(const float* __restrict__ s,
                                                    u16* __restrict__ d, long n4) {
  long stride = (long)gridDim.x * 256;
  for (long i = (long)blockIdx.x * 256 + threadIdx.x; i < n4; i += stride) {
    f32x4 v = *(const f32x4*)(s + i * 4);
    u16x4 o = {f2bf(v.x), f2bf(v.y), f2bf(v.z), f2bf(v.w)};
    *(u16x4*)(d + i * 4) = o;
  }
}

// dst[c][r] = src[r][c] (bf16), c in [0,CP), zero-filled for c >= C
__global__ __launch_bounds__(256) void transpose_f32_bf16(const float* __restrict__ src,
                                                          u16* __restrict__ dst,
                                                          int R, int C, int CP) {
  __shared__ float tile[32][33];
  int r0 = blockIdx.x * 32, c0 = blockIdx.y * 32;
  int tx = threadIdx.x & 31, ty = threadIdx.x >> 5;
#pragma unroll
  for (int i = 0; i < 32; i += 8) {
    int r = r0 + ty + i, c = c0 + tx;
    tile[ty + i][tx] = (r < R && c < C) ? src[(size_t)r * C + c] : 0.f;
  }
  __syncthreads();
#pragma unroll
  for (int i = 0; i < 32; i += 8) {
    int c = c0 + ty + i, r = r0 + tx;
    if (c < CP && r < R) dst[(size_t)c * R + r] = f2bf(tile[tx][ty + i]);
  }
}

// ---------------- 128x128 2-phase GEMM helpers (small GEMMs) ----------------

template <int NROW>
__device__ __forceinline__ void stage_direct(const u16* __restrict__ src, int ld,
                                             int kcol0, u16* lds, int tid) {
#pragma unroll
  for (int it = 0; it < NROW / 32; ++it) {
    int idx = it * 256 + tid;
    int row = idx >> 3, c = idx & 7;
    int cc = c ^ (row & 7);
    gld16(src + (size_t)row * ld + kcol0 + cc * 8, (char*)lds + idx * 16);
  }
}

template <int MI>
__device__ __forceinline__ void mma_step(const char* As, const char* Bs, int arow0,
                                         int brow0, int lane, f32x4 acc[MI][4]) {
  int r = lane & 15, q = lane >> 4;
#pragma unroll
  for (int ks = 0; ks < 2; ++ks) {
    short8 a[MI], b[4];
#pragma unroll
    for (int i = 0; i < MI; ++i) {
      int row = arow0 + i * 16 + r;
      a[i] = *(const short8*)(As + row * 128 + ((((ks << 2) + q) ^ (row & 7)) << 4));
    }
#pragma unroll
    for (int j = 0; j < 4; ++j) {
      int row = brow0 + j * 16 + r;
      b[j] = *(const short8*)(Bs + row * 128 + ((((ks << 2) + q) ^ (row & 7)) << 4));
    }
#pragma unroll
    for (int i = 0; i < MI; ++i)
#pragma unroll
      for (int j = 0; j < 4; ++j)
        acc[i][j] = __builtin_amdgcn_mfma_f32_16x16x32_bf16(a[i], b[j], acc[i][j], 0, 0, 0);
  }
}

// ---------------- GEMM1: edge_rep = ec @ Wpe + b -> head/tail bf16 ----------------

__global__ __launch_bounds__(256) void gemm1(const u16* __restrict__ ec,
                                             const u16* __restrict__ WpeT,
                                             const float* __restrict__ bpe,
                                             u16* __restrict__ head,
                                             u16* __restrict__ tail) {
  __shared__ __align__(16) u16 As[128 * 64];
  __shared__ __align__(16) u16 Bs[128 * 64];
  int tid = threadIdx.x, lane = tid & 63, wave = tid >> 6;
  int wrow = wave >> 1, wcol = wave & 1;
  int m0 = blockIdx.x * 128, n0 = blockIdx.y * 128;
  f32x4 z = {0.f, 0.f, 0.f, 0.f};
  f32x4 acc[4][4];
#pragma unroll
  for (int i = 0; i < 4; ++i)
#pragma unroll
    for (int j = 0; j < 4; ++j) acc[i][j] = z;

  for (int kb = 0; kb < 8; ++kb) {
    stage_direct<128>(ec + (size_t)m0 * 512, 512, kb * 64, As, tid);
    stage_direct<128>(WpeT + (size_t)n0 * 512, 512, kb * 64, Bs, tid);
    __syncthreads();
    mma_step<4>((const char*)As, (const char*)Bs, wrow * 64, wcol * 64, lane, acc);
    __syncthreads();
  }
  int r = lane & 15, q = lane >> 4;
#pragma unroll
  for (int i = 0; i < 4; ++i) {
    int e = m0 + wrow * 64 + i * 16 + q * 4;
#pragma unroll
    for (int j = 0; j < 4; ++j) {
      int c = n0 + wcol * 64 + j * 16 + r;
      float bb = bpe[c];
#pragma unroll
      for (int g = 0; g < 4; ++g) {
        float v = acc[i][j][g] + bb;
        if (c < 512) head[(size_t)(e + g) * 512 + c] = f2bf(v);
        else         tail[(size_t)(e + g) * 512 + (c - 512)] = f2bf(v);
      }
    }
  }
}

// ---- GEMM-HP: P = A(6144x512) @ BT(4096x512)^T, no bias, bf16 out ----

__global__ __launch_bounds__(256) void gemm_hp(const u16* __restrict__ A,
                                               const u16* __restrict__ BT,
                                               u16* __restrict__ P) {
  __shared__ __align__(16) u16 As[128 * 64];
  __shared__ __align__(16) u16 Bs[128 * 64];
  int tid = threadIdx.x, lane = tid & 63, wave = tid >> 6;
  int wrow = wave >> 1, wcol = wave & 1;
  int m0 = blockIdx.x * 128, n0 = blockIdx.y * 128;
  f32x4 z = {0.f, 0.f, 0.f, 0.f};
  f32x4 acc[4][4];
#pragma unroll
  for (int i = 0; i < 4; ++i)
#pragma unroll
    for (int j = 0; j < 4; ++j) acc[i][j] = z;

  for (int kb = 0; kb < 8; ++kb) {
    stage_direct<128>(A + (size_t)m0 * 512, 512, kb * 64, As, tid);
    stage_direct<128>(BT + (size_t)n0 * 512, 512, kb * 64, Bs, tid);
    __syncthreads();
    mma_step<4>((const char*)As, (const char*)Bs, wrow * 64, wcol * 64, lane, acc);
    __syncthreads();
  }
  int r = lane & 15, q = lane >> 4;
#pragma unroll
  for (int i = 0; i < 4; ++i) {
    int e = m0 + wrow * 64 + i * 16 + q * 4;
#pragma unroll
    for (int j = 0; j < 4; ++j) {
      int c = n0 + wcol * 64 + j * 16 + r;
#pragma unroll
      for (int g = 0; g < 4; ++g)
        P[(size_t)(e + g) * 4096 + c] = f2bf(acc[i][j][g]);
    }
  }
}

// ================ 256x256 union GEMM — A-only LDS, B direct from L2 ================
// B fragments load straight from global (WupT L2-resident: 4 panels x 1MB per XCD)
// into registers, double-buffered one tile ahead. LDS holds only A (64KB: 2buf x
// 2kh x 16KB quarters) -> LDS port traffic drops ~40%. Boundaries vmcnt(6):
// FIFO = 2 A-DMA + 4 B-loads. BUGFIX vs R14: gA0/gA1 advance after prologue
// (A-tiles were staged one K-step late -> wrong result).
// prod = (U @ WupT^T + bup) * (Hp[p0] + Tp[p1] + bpc); fused gemm4 K-partial.
// A quarter layout: [row 0..255][32 kcols]; chunk swizzle c4 ^ ((row>>1)&3).
// Supertile swizzle: each XCD's 32 blocks = 8m x 4n supertile.

__global__ __launch_bounds__(512, 2) void gemm_union_fuse4(
    const u16* __restrict__ U, const u16* __restrict__ WupT,
    const float* __restrict__ bup, const float* __restrict__ bpc,
    const u16* __restrict__ Hp, const u16* __restrict__ Tp,
    const int* __restrict__ pair, const u16* __restrict__ WrelT,
    u16* __restrict__ Pp) {
  extern __shared__ __align__(16) u16 lds[];   // 131072 B alloc; K-loop uses 64KB
  const int tid = threadIdx.x, lane = tid & 63, wave = tid >> 6;
  const int wm = wave >> 2, wn = wave & 3;
  const int r = lane & 15, q = lane >> 4;

  // hierarchical supertile swizzle: 3072 blocks = 192m x 16n tiles
  int bid = blockIdx.x;
  int xcd = bid & 7, seq = bid >> 3;          // seq 0..383
  int st = seq >> 5, within = seq & 31;       // 12 supertiles/XCD, 32 blocks each
  int gst = xcd * 12 + st;                    // 0..95 = 24 msuper x 4 nsuper
  int nsuper = gst / 24, msuper = gst % 24;
  int m0 = (msuper * 8 + (within >> 2)) * 256;
  int n0 = (nsuper * 4 + (within & 3)) * 256;

  f32x4 acc[8][4];
  f32x4 z = {0.f, 0.f, 0.f, 0.f};
#pragma unroll
  for (int i = 0; i < 8; ++i)
#pragma unroll
    for (int j = 0; j < 4; ++j) acc[i][j] = z;

  // LDS A quarters: (buf,kh) at (buf*2+kh)*8192 u16 (16KB each)
  int chunk = (q ^ ((r >> 1) & 3)) << 4;
  const char* cA0 = (const char*)lds + (wm * 128 + r) * 64 + chunk;   // buf0 base
  const char* cA1 = cA0 + 32768;                                      // buf1 base

  // staging addresses (advance +64 u16 per K-tile)
  int srow = tid >> 2, sc4 = tid & 3;
  int sswz = (sc4 ^ ((srow >> 1) & 3)) * 8;
  const u16* gA0 = U + (size_t)(m0 + srow) * 2048 + sswz;
  const u16* gA1 = U + (size_t)(m0 + 128 + srow) * 2048 + sswz;
  // B fragment base: row (n0 + wn*64 + r), 16B chunk at q*8; nj offset = nj*16*2048
  const u16* gB = WupT + (size_t)(n0 + wn * 64 + r) * 2048 + q * 8;

  auto STGA = [&](int khu /*u16: 0|32*/, int qb /*u16 quarter base*/) {
    gld16(gA0 + khu, lds + qb + tid * 8);
    gld16(gA1 + khu, lds + qb + 4096 + tid * 8);
  };

  short8 a[4], b0[4], b1[4];

  // prologue: B(0,k0), B(0,k1), A(0,k0), A(0,k1); wait A(0,k0) (drains B too)
#pragma unroll
  for (int nj = 0; nj < 4; ++nj) b0[nj] = *(const short8*)(gB + (size_t)nj * 32768);
#pragma unroll
  for (int nj = 0; nj < 4; ++nj) b1[nj] = *(const short8*)(gB + 32 + (size_t)nj * 32768);
  STGA(0, 0);
  STGA(32, 8192);
  gA0 += 64; gA1 += 64;              // BUGFIX: now pointing at tile 1
  boundary<2>();

  auto kstep = [&](auto curc, bool more) {
    constexpr int CUR = decltype(curc)::value;
    constexpr int NXT = CUR ^ 1;
    const char* pa = CUR ? cA1 : cA0;

    // ---- P0: kh0, mi 0..3 x b0; stage A(t+1,k0) ----
#pragma unroll
    for (int mi = 0; mi < 4; ++mi) a[mi] = *(const short8*)(pa + mi * 1024);
    if (more) STGA(0, (NXT * 2 + 0) * 8192);
    __builtin_amdgcn_s_setprio(1);
#pragma unroll
    for (int mi = 0; mi < 4; ++mi)
#pragma unroll
      for (int nj = 0; nj < 4; ++nj)
        acc[mi][nj] = __builtin_amdgcn_mfma_f32_16x16x32_bf16(a[mi], b0[nj], acc[mi][nj], 0, 0, 0);
    __builtin_amdgcn_s_setprio(0);

    // ---- P1: kh0, mi 4..7 x b0; then reload b0 <- B(t+1,k0) ----
#pragma unroll
    for (int mi = 0; mi < 4; ++mi) a[mi] = *(const short8*)(pa + (mi + 4) * 1024);
    __builtin_amdgcn_s_setprio(1);
#pragma unroll
    for (int mi = 0; mi < 4; ++mi)
#pragma unroll
      for (int nj = 0; nj < 4; ++nj)
        acc[mi + 4][nj] = __builtin_amdgcn_mfma_f32_16x16x32_bf16(a[mi], b0[nj], acc[mi + 4][nj], 0, 0, 0);
    __builtin_amdgcn_s_setprio(0);
    if (more) {
#pragma unroll
      for (int nj = 0; nj < 4; ++nj) b0[nj] = *(const short8*)(gB + 64 + (size_t)nj * 32768);
    }

    // ---- mid boundary: A(t,k1) landed (keep newest 6 = 2 DMA + 4 B) ----
    if (more) boundary<6>(); else boundary<0>();

    // ---- P2: kh1, mi 0..3 x b1; stage A(t+1,k1) ----
#pragma unroll
    for (int mi = 0; mi < 4; ++mi) a[mi] = *(const short8*)(pa + 16384 + mi * 1024);
    if (more) STGA(32, (NXT * 2 + 1) * 8192);
    __builtin_amdgcn_s_setprio(1);
#pragma unroll
    for (int mi = 0; mi < 4; ++mi)
#pragma unroll
      for (int nj = 0; nj < 4; ++nj)
        acc[mi][nj] = __builtin_amdgcn_mfma_f32_16x16x32_bf16(a[mi], b1[nj], acc[mi][nj], 0, 0, 0);
    __builtin_amdgcn_s_setprio(0);

    // ---- P3: kh1, mi 4..7 x b1; then reload b1 <- B(t+1,k1) ----
#pragma unroll
    for (int mi = 0; mi < 4; ++mi) a[mi] = *(const short8*)(pa + 16384 + (mi + 4) * 1024);
    __builtin_amdgcn_s_setprio(1);
#pragma unroll
    for (int mi = 0; mi < 4; ++mi)
#pragma unroll
      for (int nj = 0; nj < 4; ++nj)
        acc[mi + 4][nj] = __builtin_amdgcn_mfma_f32_16x16x32_bf16(a[mi], b1[nj], acc[mi + 4][nj], 0, 0, 0);
    __builtin_amdgcn_s_setprio(0);
    if (more) {
#pragma unroll
      for (int nj = 0; nj < 4; ++nj) b1[nj] = *(const short8*)(gB + 96 + (size_t)nj * 32768);
    }

    gA0 += 64; gA1 += 64; gB += 64;
    // ---- end boundary: A(t+1,k0) landed (keep newest 6 = 2 DMA + 4 B) ----
    if (more) boundary<6>();
  };

  for (int tt = 0; tt < 16; ++tt) {
    kstep(IC<0>{}, true);
    kstep(IC<1>{}, tt < 15);
  }

  __syncthreads();   // full drain + barrier before LDS reuse by epilogue

  // ---- ep1: acc (+bup) -> per-wave LDS region (bf16) ----
  // wave region: 16 KiB at lds + wave*8192 (u16), layout [128 rows][64 cols],
  // 16B col-chunk ch stored at ch ^ (row&7).
  u16* Uw = lds + (wave << 13);
#pragma unroll
  for (int mi = 0; mi < 8; ++mi) {
#pragma unroll
    for (int nj = 0; nj < 4; ++nj) {
      int col = nj * 16 + r;
      float bb = bup[n0 + wn * 64 + col];
#pragma unroll
      for (int g = 0; g < 4; ++g) {
        int rw = mi * 16 + q * 4 + g;
        int byte_off = rw * 128 + ((((col >> 3) ^ (rw & 7)) << 4)) + (col & 7) * 2;
        *(u16*)((char*)Uw + byte_off) = f2bf(acc[mi][nj][g] + bb);
      }
    }
  }
  asm volatile("s_waitcnt lgkmcnt(0)" ::: "memory");
  __builtin_amdgcn_sched_barrier(0);

  // ---- ep2: per-lane 2 rows; vector gather + multiply; prod back into LDS ----
  int c0 = n0 + wn * 64;
#pragma unroll
  for (int rr = 0; rr < 2; ++rr) {
    int lr = lane * 2 + rr;                  // 0..127 within wave region
    int e = m0 + wm * 128 + lr;
    int h = pair[2 * e], tt = pair[2 * e + 1];
    const u16* hp = Hp + (size_t)h * 4096 + c0;
    const u16* tp = Tp + (size_t)tt * 4096 + c0;
#pragma unroll
    for (int ch = 0; ch < 8; ++ch) {
      u16x8 hv = *(const u16x8*)(hp + ch * 8);
      u16x8 tv = *(const u16x8*)(tp + ch * 8);
      u16* slot = (u16*)((char*)Uw + lr * 128 + ((ch ^ (lr & 7)) << 4));
      u16x8 uv = *(u16x8*)slot;
      u16x8 o;
#pragma unroll
      for (int k = 0; k < 8; ++k) {
        float p = bf2f(hv[k]) + bf2f(tv[k]) + bpc[c0 + ch * 8 + k];
        o[k] = f2bf(bf2f(uv[k]) * p);
      }
      *(u16x8*)slot = o;   // prod tile now lives in LDS
    }
  }
  __syncthreads();   // all regions' prod visible to all waves

  // ---- ep3: mini-GEMM  Pp_partial = prod_tile(256x256) @ WrelT[n0..n0+255]^T ----
  f32x4 acc2[2][4];
#pragma unroll
  for (int i = 0; i < 2; ++i)
#pragma unroll
    for (int j = 0; j < 4; ++j) acc2[i][j] = z;

#pragma unroll
  for (int ks = 0; ks < 8; ++ks) {         // k0 = ks*32
    int wn_k = ks >> 1;                    // region col-group
    int cb = (ks & 1) * 4;                 // chunk base within region
    short8 a2[2], b2[4];
#pragma unroll
    for (int i = 0; i < 2; ++i) {
      int rr2 = wave * 32 + i * 16 + r;    // tile row
      int reg = ((rr2 >> 7) << 2) | wn_k;  // region id = wm_r*4 + wn_k
      int lr2 = rr2 & 127;
      int ch = cb + q;
      a2[i] = *(const short8*)((char*)lds + reg * 16384 + lr2 * 128 +
                               ((ch ^ (lr2 & 7)) << 4));
    }
#pragma unroll
    for (int j = 0; j < 4; ++j)            // WrelT: [64 n][4096 k], zero-padded n>=51
      b2[j] = *(const short8*)(WrelT + (size_t)(j * 16 + r) * 4096 + n0 + ks * 32 + q * 8);
#pragma unroll
    for (int i = 0; i < 2; ++i)
#pragma unroll
      for (int j = 0; j < 4; ++j)
        acc2[i][j] = __builtin_amdgcn_mfma_f32_16x16x32_bf16(a2[i], b2[j], acc2[i][j], 0, 0, 0);
  }

  // ---- ep4: store bf16 partial [nt][e][64] ----
  int nt = n0 >> 8;
#pragma unroll
  for (int i = 0; i < 2; ++i) {
#pragma unroll
    for (int j = 0; j < 4; ++j) {
      int col = j * 16 + r;
#pragma unroll
      for (int g = 0; g < 4; ++g) {
        int e = m0 + wave * 32 + i * 16 + q * 4 + g;
        Pp[((size_t)nt * 49152 + e) * 64 + col] = f2bf(acc2[i][j][g]);
      }
    }
  }
}

// ---- reduce: out[e][c] = sum_nt Pp[nt][e][c] + brel[c] + freq[bidx(e)][c] ----

__global__ __launch_bounds__(256) void reduce_out(const u16* __restrict__ Pp,
                                                  const float* __restrict__ brel,
                                                  const float* __restrict__ freq,
                                                  const int* __restrict__ obj,
                                                  const int* __restrict__ pair,
                                                  float* __restrict__ out) {
  int e = blockIdx.x * 4 + (threadIdx.x >> 6);
  int c = threadIdx.x & 63;
  const u16* p = Pp + (size_t)e * 64 + c;
  float s = 0.f;
#pragma unroll
  for (int nt = 0; nt < 16; ++nt) s += bf2f(p[(size_t)nt * 49152 * 64]);
  if (c < 51) {
    int bidx = obj[pair[2 * e]] * 151 + obj[pair[2 * e + 1]];
    out[(size_t)e * 51 + c] = s + brel[c] + freq[(size_t)bidx * 51 + c];
  }
}

// ---------------- launcher ----------------

extern "C" void kernel_launch(void* const* d_in, const int* in_sizes, int n_in,
                              void* d_out, int out_size, void* d_ws, size_t ws_size,
                              hipStream_t stream) {
  const float* edge_ctx = (const float*)d_in[0];   // 6144 x 512
  const float* unionf   = (const float*)d_in[1];   // 49152 x 2048
  const float* Wpe      = (const float*)d_in[2];   // 512 x 1024
  const float* bpe      = (const float*)d_in[3];   // 1024
  const float* Wpc      = (const float*)d_in[4];   // 1024 x 4096
  const float* bpc      = (const float*)d_in[5];   // 4096
  const float* Wup      = (const float*)d_in[6];   // 2048 x 4096
  const float* bup      = (const float*)d_in[7];   // 4096
  const float* Wrel     = (const float*)d_in[8];   // 4096 x 51
  const float* brel     = (const float*)d_in[9];   // 51
  const float* freq     = (const float*)d_in[10];  // 22801 x 51
  const int*   obj      = (const int*)d_in[11];    // 6144
  const int*   pair     = (const int*)d_in[12];    // 49152 x 2
  float* out = (float*)d_out;

  u16* ws = (u16*)d_ws;
  // workspace layout (u16 elems)
  u16* Pp      = ws;                     // 16*49152*64 bf16 = 100 MB
  u16* ub      = ws + 201326592;         // 49152*2048
  u16* ec      = ws + 301989888;         // 6144*512
  u16* head    = ws + 305135616;         // 6144*512
  u16* tail    = ws + 308281344;         // 6144*512
  u16* WpeT    = ws + 311427072;         // 1024*512
  u16* WpcTopT = ws + 311951360;         // 4096*512
  u16* WpcBotT = ws + 314048512;         // 4096*512
  u16* WupT    = ws + 316145664;         // 4096*2048
  u16* WrelT   = ws + 324534272;         // 64*4096
  u16* Hp      = ws + 324796416;         // 6144*4096
  u16* Tp      = ws + 349962240;         // 6144*4096  (end 375128064)

  // conversions
  cvt_f32_bf16<<<768, 256, 0, stream>>>(edge_ctx, ec, 786432);
  cvt_f32_bf16<<<4096, 256, 0, stream>>>(unionf, ub, 25165824);
  transpose_f32_bf16<<<dim3(16, 32), 256, 0, stream>>>(Wpe, WpeT, 512, 1024, 1024);
  transpose_f32_bf16<<<dim3(16, 128), 256, 0, stream>>>(Wpc, WpcTopT, 512, 4096, 4096);
  transpose_f32_bf16<<<dim3(16, 128), 256, 0, stream>>>(Wpc + (size_t)512 * 4096, WpcBotT, 512, 4096, 4096);
  transpose_f32_bf16<<<dim3(64, 128), 256, 0, stream>>>(Wup, WupT, 2048, 4096, 4096);
  transpose_f32_bf16<<<dim3(128, 2), 256, 0, stream>>>(Wrel, WrelT, 4096, 51, 64);

  // GEMM chain
  gemm1<<<dim3(48, 8), 256, 0, stream>>>(ec, WpeT, bpe, head, tail);
  gemm_hp<<<dim3(48, 32), 256, 0, stream>>>(head, WpcTopT, Hp);
  gemm_hp<<<dim3(48, 32), 256, 0, stream>>>(tail, WpcBotT, Tp);
  gemm_union_fuse4<<<3072, 512, 131072, stream>>>(ub, WupT, bup, bpc, Hp, Tp, pair, WrelT, Pp);
  reduce_out<<<12288, 256, 0, stream>>>(Pp, brel, freq, obj, pair, out);
}

// Round 16
// 1237.332 us; speedup vs baseline: 1.3054x; 1.3054x over previous
//
#include <hip/hip_runtime.h>

typedef unsigned short u16;
typedef __attribute__((ext_vector_type(4))) float f32x4;
typedef __attribute__((ext_vector_type(4))) u16 u16x4;
typedef __attribute__((ext_vector_type(8))) u16 u16x8;
typedef __attribute__((ext_vector_type(8))) short short8;

template <int V> struct IC { static constexpr int value = V; };

__device__ __forceinline__ u16 f2bf(float f) {
  unsigned int u = __builtin_bit_cast(unsigned int, f);
  u += 0x7FFFu + ((u >> 16) & 1u);   // RNE
  return (u16)(u >> 16);
}
__device__ __forceinline__ float bf2f(u16 b) {
  unsigned int u = ((unsigned int)b) << 16;
  return __builtin_bit_cast(float, u);
}

// async global->LDS, 16B per lane; dest must be wave-linear (base + lane*16)
__device__ __forceinline__ void gld16(const void* g, void* l) {
  __builtin_amdgcn_global_load_lds(
      (const __attribute__((address_space(1))) unsigned int*)g,
      (__attribute__((address_space(3))) unsigned int*)l, 16, 0, 0);
}

template <int N>
__device__ __forceinline__ void boundary() {
  asm volatile("s_waitcnt vmcnt(%0)" ::"n"(N) : "memory");
  __builtin_amdgcn_s_barrier();
  asm volatile("" ::: "memory");
  __builtin_amdgcn_sched_barrier(0);
}

// ---------------- conversion / transpose ----------------

__global__ __launch_bounds__(256) void cvt_f32_bf16(const float* __restrict__ s,
                                                    u16* __restrict__ d, long n4) {
  long stride = (long)gridDim.x * 256;
  for (long i = (long)blockIdx.x * 256 + threadIdx.x; i < n4; i += stride) {
    f32x4 v = *(const f32x4*)(s + i * 4);
    u16x4 o = {f2bf(v.x), f2bf(v.y), f2bf(v.z), f2bf(v.w)};
    *(u16x4*)(d + i * 4) = o;
  }
}

// dst[c][r] = src[r][c] (bf16), c in [0,CP), zero-filled for c >= C
__global__ __launch_bounds__(256) void transpose_f32_bf16(const float* __restrict__ src,
                                                          u16* __restrict__ dst,
                                                          int R, int C, int CP) {
  __shared__ float tile[32][33];
  int r0 = blockIdx.x * 32, c0 = blockIdx.y * 32;
  int tx = threadIdx.x & 31, ty = threadIdx.x >> 5;
#pragma unroll
  for (int i = 0; i < 32; i += 8) {
    int r = r0 + ty + i, c = c0 + tx;
    tile[ty + i][tx] = (r < R && c < C) ? src[(size_t)r * C + c] : 0.f;
  }
  __syncthreads();
#pragma unroll
  for (int i = 0; i < 32; i += 8) {
    int c = c0 + ty + i, r = r0 + tx;
    if (c < CP && r < R) dst[(size_t)c * R + r] = f2bf(tile[tx][ty + i]);
  }
}

// ---------------- 128x128 2-phase GEMM helpers (small GEMMs) ----------------

template <int NROW>
__device__ __forceinline__ void stage_direct(const u16* __restrict__ src, int ld,
                                             int kcol0, u16* lds, int tid) {
#pragma unroll
  for (int it = 0; it < NROW / 32; ++it) {
    int idx = it * 256 + tid;
    int row = idx >> 3, c = idx & 7;
    int cc = c ^ (row & 7);
    gld16(src + (size_t)row * ld + kcol0 + cc * 8, (char*)lds + idx * 16);
  }
}

template <int MI>
__device__ __forceinline__ void mma_step(const char* As, const char* Bs, int arow0,
                                         int brow0, int lane, f32x4 acc[MI][4]) {
  int r = lane & 15, q = lane >> 4;
#pragma unroll
  for (int ks = 0; ks < 2; ++ks) {
    short8 a[MI], b[4];
#pragma unroll
    for (int i = 0; i < MI; ++i) {
      int row = arow0 + i * 16 + r;
      a[i] = *(const short8*)(As + row * 128 + ((((ks << 2) + q) ^ (row & 7)) << 4));
    }
#pragma unroll
    for (int j = 0; j < 4; ++j) {
      int row = brow0 + j * 16 + r;
      b[j] = *(const short8*)(Bs + row * 128 + ((((ks << 2) + q) ^ (row & 7)) << 4));
    }
#pragma unroll
    for (int i = 0; i < MI; ++i)
#pragma unroll
      for (int j = 0; j < 4; ++j)
        acc[i][j] = __builtin_amdgcn_mfma_f32_16x16x32_bf16(a[i], b[j], acc[i][j], 0, 0, 0);
  }
}

// ---------------- GEMM1: edge_rep = ec @ Wpe + b -> head/tail bf16 ----------------

__global__ __launch_bounds__(256) void gemm1(const u16* __restrict__ ec,
                                             const u16* __restrict__ WpeT,
                                             const float* __restrict__ bpe,
                                             u16* __restrict__ head,
                                             u16* __restrict__ tail) {
  __shared__ __align__(16) u16 As[128 * 64];
  __shared__ __align__(16) u16 Bs[128 * 64];
  int tid = threadIdx.x, lane = tid & 63, wave = tid >> 6;
  int wrow = wave >> 1, wcol = wave & 1;
  int m0 = blockIdx.x * 128, n0 = blockIdx.y * 128;
  f32x4 z = {0.f, 0.f, 0.f, 0.f};
  f32x4 acc[4][4];
#pragma unroll
  for (int i = 0; i < 4; ++i)
#pragma unroll
    for (int j = 0; j < 4; ++j) acc[i][j] = z;

  for (int kb = 0; kb < 8; ++kb) {
    stage_direct<128>(ec + (size_t)m0 * 512, 512, kb * 64, As, tid);
    stage_direct<128>(WpeT + (size_t)n0 * 512, 512, kb * 64, Bs, tid);
    __syncthreads();
    mma_step<4>((const char*)As, (const char*)Bs, wrow * 64, wcol * 64, lane, acc);
    __syncthreads();
  }
  int r = lane & 15, q = lane >> 4;
#pragma unroll
  for (int i = 0; i < 4; ++i) {
    int e = m0 + wrow * 64 + i * 16 + q * 4;
#pragma unroll
    for (int j = 0; j < 4; ++j) {
      int c = n0 + wcol * 64 + j * 16 + r;
      float bb = bpe[c];
#pragma unroll
      for (int g = 0; g < 4; ++g) {
        float v = acc[i][j][g] + bb;
        if (c < 512) head[(size_t)(e + g) * 512 + c] = f2bf(v);
        else         tail[(size_t)(e + g) * 512 + (c - 512)] = f2bf(v);
      }
    }
  }
}

// ---- GEMM-HP: P = A(6144x512) @ BT(4096x512)^T, no bias, bf16 out ----

__global__ __launch_bounds__(256) void gemm_hp(const u16* __restrict__ A,
                                               const u16* __restrict__ BT,
                                               u16* __restrict__ P) {
  __shared__ __align__(16) u16 As[128 * 64];
  __shared__ __align__(16) u16 Bs[128 * 64];
  int tid = threadIdx.x, lane = tid & 63, wave = tid >> 6;
  int wrow = wave >> 1, wcol = wave & 1;
  int m0 = blockIdx.x * 128, n0 = blockIdx.y * 128;
  f32x4 z = {0.f, 0.f, 0.f, 0.f};
  f32x4 acc[4][4];
#pragma unroll
  for (int i = 0; i < 4; ++i)
#pragma unroll
    for (int j = 0; j < 4; ++j) acc[i][j] = z;

  for (int kb = 0; kb < 8; ++kb) {
    stage_direct<128>(A + (size_t)m0 * 512, 512, kb * 64, As, tid);
    stage_direct<128>(BT + (size_t)n0 * 512, 512, kb * 64, Bs, tid);
    __syncthreads();
    mma_step<4>((const char*)As, (const char*)Bs, wrow * 64, wcol * 64, lane, acc);
    __syncthreads();
  }
  int r = lane & 15, q = lane >> 4;
#pragma unroll
  for (int i = 0; i < 4; ++i) {
    int e = m0 + wrow * 64 + i * 16 + q * 4;
#pragma unroll
    for (int j = 0; j < 4; ++j) {
      int c = n0 + wcol * 64 + j * 16 + r;
#pragma unroll
      for (int g = 0; g < 4; ++g)
        P[(size_t)(e + g) * 4096 + c] = f2bf(acc[i][j][g]);
    }
  }
}

// ================ 256x256 union GEMM — R9 schedule + base+imm LDS addressing ====
// (reverted to the best-measured variant: R13, union ~1003 us, total ~1240 us)
// prod = (U @ WupT^T + bup) * (Hp[p0] + Tp[p1] + bpc); fused gemm4 K-partial.
// LDS (128 KiB): quarter(buf,mat,kh) = 16384 B at (buf*4+mat*2+kh)*16384.
// Quarter layout: [row 0..255][32 kcols]; 16B chunk swizzle s(row)=(row>>1)&3.
// Supertile swizzle: each XCD's 32 blocks = 8m x 4n supertile.

__global__ __launch_bounds__(512, 2) void gemm_union_fuse4(
    const u16* __restrict__ U, const u16* __restrict__ WupT,
    const float* __restrict__ bup, const float* __restrict__ bpc,
    const u16* __restrict__ Hp, const u16* __restrict__ Tp,
    const int* __restrict__ pair, const u16* __restrict__ WrelT,
    u16* __restrict__ Pp) {
  extern __shared__ __align__(16) u16 lds[];   // 65536 u16 = 128 KiB
  const int tid = threadIdx.x, lane = tid & 63, wave = tid >> 6;
  const int wm = wave >> 2, wn = wave & 3;
  const int r = lane & 15, q = lane >> 4;

  // hierarchical supertile swizzle: 3072 blocks = 192m x 16n tiles
  int bid = blockIdx.x;
  int xcd = bid & 7, seq = bid >> 3;          // seq 0..383
  int st = seq >> 5, within = seq & 31;       // 12 supertiles/XCD, 32 blocks each
  int gst = xcd * 12 + st;                    // 0..95 = 24 msuper x 4 nsuper
  int nsuper = gst / 24, msuper = gst % 24;
  int m0 = (msuper * 8 + (within >> 2)) * 256;
  int n0 = (nsuper * 4 + (within & 3)) * 256;

  f32x4 acc[8][4];
  f32x4 z = {0.f, 0.f, 0.f, 0.f};
#pragma unroll
  for (int i = 0; i < 8; ++i)
#pragma unroll
    for (int j = 0; j < 4; ++j) acc[i][j] = z;

  // ---- precomputed LDS read bases (lane-invariant across the whole K-loop) ----
  int chunk = (q ^ ((r >> 1) & 3)) << 4;                 // byte offset of 16B chunk
  const char* cA0 = (const char*)lds + (wm * 128 + r) * 64 + chunk;            // buf0 A
  const char* cA1 = cA0 + 65536;                                               // buf1 A
  const char* cB0 = (const char*)lds + 32768 + (wn * 64 + r) * 64 + chunk;     // buf0 B
  const char* cB1 = cB0 + 65536;                                               // buf1 B

  // ---- precomputed staging addresses (advance +64 u16 per K-step) ----
  int srow = tid >> 2, sc4 = tid & 3;
  int sswz = (sc4 ^ ((srow >> 1) & 3)) * 8;              // u16 units
  const u16* gA0 = U + (size_t)(m0 + srow) * 2048 + sswz;
  const u16* gA1 = U + (size_t)(m0 + 128 + srow) * 2048 + sswz;
  const u16* gB0 = WupT + (size_t)(n0 + srow) * 2048 + sswz;
  const u16* gB1 = WupT + (size_t)(n0 + 128 + srow) * 2048 + sswz;

  // STG: stage one (mat, kh) quarter: 2 loads/thread; all LDS offsets literal
  auto STG = [&](const u16* g0, const u16* g1, int khb /*bytes*/, int qb /*u16*/) {
    gld16((const char*)g0 + khb, lds + qb + tid * 8);
    gld16((const char*)g1 + khb, lds + qb + 4096 + tid * 8);
  };

  short8 a[4], b[4];

  // prologue: tile 0 into buf0 (kt=0): A kh0, B kh0, A kh1, B kh1
  STG(gA0, gA1, 0, 0);
  STG(gB0, gB1, 0, 2 * 8192);
  STG(gA0, gA1, 64, 1 * 8192);
  STG(gB0, gB1, 64, 3 * 8192);
  gA0 += 64; gA1 += 64; gB0 += 64; gB1 += 64;   // now at kt=1
  boundary<4>();   // A kh0 + B kh0 landed

  // one K-step; CUR is constexpr (buf), stages tile t+1 into NXT
  auto kstep = [&](auto curc) {
    constexpr int CUR = decltype(curc)::value;
    constexpr int NXT = CUR ^ 1;
    const char* pa = CUR ? cA1 : cA0;
    const char* pb = CUR ? cB1 : cB0;

    // ---- P0: kh=0, mi 0..3 ----
#pragma unroll
    for (int nj = 0; nj < 4; ++nj) b[nj] = *(const short8*)(pb + nj * 1024);
#pragma unroll
    for (int mi = 0; mi < 4; ++mi) a[mi] = *(const short8*)(pa + mi * 1024);
    STG(gA0, gA1, 0, (NXT * 4 + 0) * 8192);
    __builtin_amdgcn_s_setprio(1);
#pragma unroll
    for (int mi = 0; mi < 4; ++mi)
#pragma unroll
      for (int nj = 0; nj < 4; ++nj)
        acc[mi][nj] = __builtin_amdgcn_mfma_f32_16x16x32_bf16(a[mi], b[nj], acc[mi][nj], 0, 0, 0);
    __builtin_amdgcn_s_setprio(0);

    // ---- P1: kh=0, mi 4..7 ----
#pragma unroll
    for (int mi = 0; mi < 4; ++mi) a[mi] = *(const short8*)(pa + (mi + 4) * 1024);
    STG(gB0, gB1, 0, (NXT * 4 + 2) * 8192);
    __builtin_amdgcn_s_setprio(1);
#pragma unroll
    for (int mi = 0; mi < 4; ++mi)
#pragma unroll
      for (int nj = 0; nj < 4; ++nj)
        acc[mi + 4][nj] = __builtin_amdgcn_mfma_f32_16x16x32_bf16(a[mi], b[nj], acc[mi + 4][nj], 0, 0, 0);
    __builtin_amdgcn_s_setprio(0);

    // ---- mid boundary: (t,kh1) landed ----
    boundary<4>();

    // ---- P2: kh=1, mi 0..3 ----
#pragma unroll
    for (int nj = 0; nj < 4; ++nj) b[nj] = *(const short8*)(pb + 16384 + nj * 1024);
#pragma unroll
    for (int mi = 0; mi < 4; ++mi) a[mi] = *(const short8*)(pa + 16384 + mi * 1024);
    STG(gA0, gA1, 64, (NXT * 4 + 1) * 8192);
    __builtin_amdgcn_s_setprio(1);
#pragma unroll
    for (int mi = 0; mi < 4; ++mi)
#pragma unroll
      for (int nj = 0; nj < 4; ++nj)
        acc[mi][nj] = __builtin_amdgcn_mfma_f32_16x16x32_bf16(a[mi], b[nj], acc[mi][nj], 0, 0, 0);
    __builtin_amdgcn_s_setprio(0);

    // ---- P3: kh=1, mi 4..7 ----
#pragma unroll
    for (int mi = 0; mi < 4; ++mi) a[mi] = *(const short8*)(pa + 16384 + (mi + 4) * 1024);
    STG(gB0, gB1, 64, (NXT * 4 + 3) * 8192);
    __builtin_amdgcn_s_setprio(1);
#pragma unroll
    for (int mi = 0; mi < 4; ++mi)
#pragma unroll
      for (int nj = 0; nj < 4; ++nj)
        acc[mi + 4][nj] = __builtin_amdgcn_mfma_f32_16x16x32_bf16(a[mi], b[nj], acc[mi + 4][nj], 0, 0, 0);
    __builtin_amdgcn_s_setprio(0);

    gA0 += 64; gA1 += 64; gB0 += 64; gB1 += 64;
    // ---- end boundary: (t+1,kh0) landed ----
    boundary<4>();
  };

  for (int tt = 0; tt < 15; ++tt) {   // t = 0..29
    kstep(IC<0>{});
    kstep(IC<1>{});
  }
  kstep(IC<0>{});                      // t = 30 (stages tile 31 into buf1)

  // ---- t = 31 (CUR=1): no staging ----
  {
    const char* pa = cA1;
    const char* pb = cB1;
#pragma unroll
    for (int nj = 0; nj < 4; ++nj) b[nj] = *(const short8*)(pb + nj * 1024);
#pragma unroll
    for (int mi = 0; mi < 4; ++mi) a[mi] = *(const short8*)(pa + mi * 1024);
    __builtin_amdgcn_s_setprio(1);
#pragma unroll
    for (int mi = 0; mi < 4; ++mi)
#pragma unroll
      for (int nj = 0; nj < 4; ++nj)
        acc[mi][nj] = __builtin_amdgcn_mfma_f32_16x16x32_bf16(a[mi], b[nj], acc[mi][nj], 0, 0, 0);
    __builtin_amdgcn_s_setprio(0);
#pragma unroll
    for (int mi = 0; mi < 4; ++mi) a[mi] = *(const short8*)(pa + (mi + 4) * 1024);
    __builtin_amdgcn_s_setprio(1);
#pragma unroll
    for (int mi = 0; mi < 4; ++mi)
#pragma unroll
      for (int nj = 0; nj < 4; ++nj)
        acc[mi + 4][nj] = __builtin_amdgcn_mfma_f32_16x16x32_bf16(a[mi], b[nj], acc[mi + 4][nj], 0, 0, 0);
    __builtin_amdgcn_s_setprio(0);

    boundary<0>();   // drain: (31,kh1) landed

#pragma unroll
    for (int nj = 0; nj < 4; ++nj) b[nj] = *(const short8*)(pb + 16384 + nj * 1024);
#pragma unroll
    for (int mi = 0; mi < 4; ++mi) a[mi] = *(const short8*)(pa + 16384 + mi * 1024);
    __builtin_amdgcn_s_setprio(1);
#pragma unroll
    for (int mi = 0; mi < 4; ++mi)
#pragma unroll
      for (int nj = 0; nj < 4; ++nj)
        acc[mi][nj] = __builtin_amdgcn_mfma_f32_16x16x32_bf16(a[mi], b[nj], acc[mi][nj], 0, 0, 0);
    __builtin_amdgcn_s_setprio(0);
#pragma unroll
    for (int mi = 0; mi < 4; ++mi) a[mi] = *(const short8*)(pa + 16384 + (mi + 4) * 1024);
    __builtin_amdgcn_s_setprio(1);
#pragma unroll
    for (int mi = 0; mi < 4; ++mi)
#pragma unroll
      for (int nj = 0; nj < 4; ++nj)
        acc[mi + 4][nj] = __builtin_amdgcn_mfma_f32_16x16x32_bf16(a[mi], b[nj], acc[mi + 4][nj], 0, 0, 0);
    __builtin_amdgcn_s_setprio(0);
  }

  __syncthreads();   // full drain + barrier before LDS reuse by epilogue

  // ---- ep1: acc (+bup) -> per-wave LDS region (bf16) ----
  // wave region: 16 KiB at lds + wave*8192 (u16), layout [128 rows][64 cols],
  // 16B col-chunk ch stored at ch ^ (row&7).
  u16* Uw = lds + (wave << 13);
#pragma unroll
  for (int mi = 0; mi < 8; ++mi) {
#pragma unroll
    for (int nj = 0; nj < 4; ++nj) {
      int col = nj * 16 + r;
      float bb = bup[n0 + wn * 64 + col];
#pragma unroll
      for (int g = 0; g < 4; ++g) {
        int rw = mi * 16 + q * 4 + g;
        int byte_off = rw * 128 + ((((col >> 3) ^ (rw & 7)) << 4)) + (col & 7) * 2;
        *(u16*)((char*)Uw + byte_off) = f2bf(acc[mi][nj][g] + bb);
      }
    }
  }
  asm volatile("s_waitcnt lgkmcnt(0)" ::: "memory");
  __builtin_amdgcn_sched_barrier(0);

  // ---- ep2: per-lane 2 rows; vector gather + multiply; prod back into LDS ----
  int c0 = n0 + wn * 64;
#pragma unroll
  for (int rr = 0; rr < 2; ++rr) {
    int lr = lane * 2 + rr;                  // 0..127 within wave region
    int e = m0 + wm * 128 + lr;
    int h = pair[2 * e], tt = pair[2 * e + 1];
    const u16* hp = Hp + (size_t)h * 4096 + c0;
    const u16* tp = Tp + (size_t)tt * 4096 + c0;
#pragma unroll
    for (int ch = 0; ch < 8; ++ch) {
      u16x8 hv = *(const u16x8*)(hp + ch * 8);
      u16x8 tv = *(const u16x8*)(tp + ch * 8);
      u16* slot = (u16*)((char*)Uw + lr * 128 + ((ch ^ (lr & 7)) << 4));
      u16x8 uv = *(u16x8*)slot;
      u16x8 o;
#pragma unroll
      for (int k = 0; k < 8; ++k) {
        float p = bf2f(hv[k]) + bf2f(tv[k]) + bpc[c0 + ch * 8 + k];
        o[k] = f2bf(bf2f(uv[k]) * p);
      }
      *(u16x8*)slot = o;   // prod tile now lives in LDS
    }
  }
  __syncthreads();   // all regions' prod visible to all waves

  // ---- ep3: mini-GEMM  Pp_partial = prod_tile(256x256) @ WrelT[n0..n0+255]^T ----
  f32x4 acc2[2][4];
#pragma unroll
  for (int i = 0; i < 2; ++i)
#pragma unroll
    for (int j = 0; j < 4; ++j) acc2[i][j] = z;

#pragma unroll
  for (int ks = 0; ks < 8; ++ks) {         // k0 = ks*32
    int wn_k = ks >> 1;                    // region col-group
    int cb = (ks & 1) * 4;                 // chunk base within region
    short8 a2[2], b2[4];
#pragma unroll
    for (int i = 0; i < 2; ++i) {
      int rr2 = wave * 32 + i * 16 + r;    // tile row
      int reg = ((rr2 >> 7) << 2) | wn_k;  // region id = wm_r*4 + wn_k
      int lr2 = rr2 & 127;
      int ch = cb + q;
      a2[i] = *(const short8*)((char*)lds + reg * 16384 + lr2 * 128 +
                               ((ch ^ (lr2 & 7)) << 4));
    }
#pragma unroll
    for (int j = 0; j < 4; ++j)            // WrelT: [64 n][4096 k], zero-padded n>=51
      b2[j] = *(const short8*)(WrelT + (size_t)(j * 16 + r) * 4096 + n0 + ks * 32 + q * 8);
#pragma unroll
    for (int i = 0; i < 2; ++i)
#pragma unroll
      for (int j = 0; j < 4; ++j)
        acc2[i][j] = __builtin_amdgcn_mfma_f32_16x16x32_bf16(a2[i], b2[j], acc2[i][j], 0, 0, 0);
  }

  // ---- ep4: store bf16 partial [nt][e][64] ----
  int nt = n0 >> 8;
#pragma unroll
  for (int i = 0; i < 2; ++i) {
#pragma unroll
    for (int j = 0; j < 4; ++j) {
      int col = j * 16 + r;
#pragma unroll
      for (int g = 0; g < 4; ++g) {
        int e = m0 + wave * 32 + i * 16 + q * 4 + g;
        Pp[((size_t)nt * 49152 + e) * 64 + col] = f2bf(acc2[i][j][g]);
      }
    }
  }
}

// ---- reduce: out[e][c] = sum_nt Pp[nt][e][c] + brel[c] + freq[bidx(e)][c] ----

__global__ __launch_bounds__(256) void reduce_out(const u16* __restrict__ Pp,
                                                  const float* __restrict__ brel,
                                                  const float* __restrict__ freq,
                                                  const int* __restrict__ obj,
                                                  const int* __restrict__ pair,
                                                  float* __restrict__ out) {
  int e = blockIdx.x * 4 + (threadIdx.x >> 6);
  int c = threadIdx.x & 63;
  const u16* p = Pp + (size_t)e * 64 + c;
  float s = 0.f;
#pragma unroll
  for (int nt = 0; nt < 16; ++nt) s += bf2f(p[(size_t)nt * 49152 * 64]);
  if (c < 51) {
    int bidx = obj[pair[2 * e]] * 151 + obj[pair[2 * e + 1]];
    out[(size_t)e * 51 + c] = s + brel[c] + freq[(size_t)bidx * 51 + c];
  }
}

// ---------------- launcher ----------------

extern "C" void kernel_launch(void* const* d_in, const int* in_sizes, int n_in,
                              void* d_out, int out_size, void* d_ws, size_t ws_size,
                              hipStream_t stream) {
  const float* edge_ctx = (const float*)d_in[0];   // 6144 x 512
  const float* unionf   = (const float*)d_in[1];   // 49152 x 2048
  const float* Wpe      = (const float*)d_in[2];   // 512 x 1024
  const float* bpe      = (const float*)d_in[3];   // 1024
  const float* Wpc      = (const float*)d_in[4];   // 1024 x 4096
  const float* bpc      = (const float*)d_in[5];   // 4096
  const float* Wup      = (const float*)d_in[6];   // 2048 x 4096
  const float* bup      = (const float*)d_in[7];   // 4096
  const float* Wrel     = (const float*)d_in[8];   // 4096 x 51
  const float* brel     = (const float*)d_in[9];   // 51
  const float* freq     = (const float*)d_in[10];  // 22801 x 51
  const int*   obj      = (const int*)d_in[11];    // 6144
  const int*   pair     = (const int*)d_in[12];    // 49152 x 2
  float* out = (float*)d_out;

  u16* ws = (u16*)d_ws;
  // workspace layout (u16 elems)
  u16* Pp      = ws;                     // 16*49152*64 bf16 = 100 MB
  u16* ub      = ws + 201326592;         // 49152*2048
  u16* ec      = ws + 301989888;         // 6144*512
  u16* head    = ws + 305135616;         // 6144*512
  u16* tail    = ws + 308281344;         // 6144*512
  u16* WpeT    = ws + 311427072;         // 1024*512
  u16* WpcTopT = ws + 311951360;         // 4096*512
  u16* WpcBotT = ws + 314048512;         // 4096*512
  u16* WupT    = ws + 316145664;         // 4096*2048
  u16* WrelT   = ws + 324534272;         // 64*4096
  u16* Hp      = ws + 324796416;         // 6144*4096
  u16* Tp      = ws + 349962240;         // 6144*4096  (end 375128064)

  // conversions
  cvt_f32_bf16<<<768, 256, 0, stream>>>(edge_ctx, ec, 786432);
  cvt_f32_bf16<<<4096, 256, 0, stream>>>(unionf, ub, 25165824);
  transpose_f32_bf16<<<dim3(16, 32), 256, 0, stream>>>(Wpe, WpeT, 512, 1024, 1024);
  transpose_f32_bf16<<<dim3(16, 128), 256, 0, stream>>>(Wpc, WpcTopT, 512, 4096, 4096);
  transpose_f32_bf16<<<dim3(16, 128), 256, 0, stream>>>(Wpc + (size_t)512 * 4096, WpcBotT, 512, 4096, 4096);
  transpose_f32_bf16<<<dim3(64, 128), 256, 0, stream>>>(Wup, WupT, 2048, 4096, 4096);
  transpose_f32_bf16<<<dim3(128, 2), 256, 0, stream>>>(Wrel, WrelT, 4096, 51, 64);

  // GEMM chain
  gemm1<<<dim3(48, 8), 256, 0, stream>>>(ec, WpeT, bpe, head, tail);
  gemm_hp<<<dim3(48, 32), 256, 0, stream>>>(head, WpcTopT, Hp);
  gemm_hp<<<dim3(48, 32), 256, 0, stream>>>(tail, WpcBotT, Tp);
  gemm_union_fuse4<<<3072, 512, 131072, stream>>>(ub, WupT, bup, bpc, Hp, Tp, pair, WrelT, Pp);
  reduce_out<<<12288, 256, 0, stream>>>(Pp, brel, freq, obj, pair, out);
}